// Round 3
// baseline (240.527 us; speedup 1.0000x reference)
//
#include <hip/hip_runtime.h>
#include <cstdint>
#include <cstddef>

// ---------------- problem constants ----------------
constexpr int CB  = 8;     // batch
constexpr int CS  = 512;   // seq len
constexpr int CH  = 768;   // hidden
constexpr int CNH = 12;    // heads
constexpr int CDH = 64;    // head dim
constexpr int CFF = 3072;  // ffn dim
constexpr int CE  = 4;     // experts
constexpr int C3H = 3 * CH;  // 2304 fused QKV width

using f32x4  = __attribute__((ext_vector_type(4))) float;
using bf16x8 = __attribute__((ext_vector_type(8))) short;

__device__ __forceinline__ short f2bf(float x) {
  union { float f; uint32_t u; } v; v.f = x;
  return (short)((v.u + 0x7fffu + ((v.u >> 16) & 1u)) >> 16);  // RNE
}

__device__ __forceinline__ void gload_lds16(const void* g, void* l) {
  __builtin_amdgcn_global_load_lds((const __attribute__((address_space(1))) void*)g,
                                   (__attribute__((address_space(3))) void*)l,
                                   16, 0, 0);
}

#define VMCNT(n)  asm volatile("s_waitcnt vmcnt(" #n ")" ::: "memory")

// ---------------- fp32 -> bf16 elementwise ----------------
__global__ void cvt_bf16_kernel(const float* __restrict__ in, short* __restrict__ out, int n4) {
  int i = blockIdx.x * blockDim.x + threadIdx.x;
  if (i < n4) {
    float4 v = ((const float4*)in)[i];
    short4 o;
    o.x = f2bf(v.x); o.y = f2bf(v.y); o.z = f2bf(v.z); o.w = f2bf(v.w);
    ((short4*)out)[i] = o;
  }
}

// ---------------- transpose+convert body: W [K,N] f32 -> Wt [N,K] bf16 ------
__device__ __forceinline__ void tpose_body(const float* __restrict__ Wb,
                                           short* __restrict__ Wtb, int K, int N) {
  __shared__ __align__(16) short Ts[64 * 68];
  const int n0 = blockIdx.x * 64, k0 = blockIdx.y * 64;
  const int t  = threadIdx.x;
  const int tn = t & 15, tk = t >> 4;
#pragma unroll
  for (int p = 0; p < 4; ++p) {
    int k = k0 + p * 16 + tk;
    float4 v = *(const float4*)(Wb + (size_t)k * N + n0 + tn * 4);
#pragma unroll
    for (int j = 0; j < 4; ++j)
      Ts[(tn * 4 + j) * 68 + p * 16 + tk] = f2bf(((const float*)&v)[j]);
  }
  __syncthreads();
#pragma unroll
  for (int p = 0; p < 4; ++p) {
    int n = n0 + p * 16 + tk;
    uint2 o = *(const uint2*)(Ts + (p * 16 + tk) * 68 + tn * 4);
    *(uint2*)(Wtb + (size_t)n * K + k0 + tn * 4) = o;
  }
}

// generic per-expert (z = expert)
__global__ void tpose_cvt_kernel(const float* __restrict__ W, short* __restrict__ Wt,
                                 int K, int N) {
  const int e = blockIdx.z;
  tpose_body(W + (size_t)e * K * N, Wt + (size_t)e * K * N, K, N);
}

// fused: z = e*4 + m; m in {0,1,2}: Wq/Wk/Wv -> Wqkvt[e][m*768 ..][768]; m==3: Wo -> Wot
__global__ void tpose4_kernel(const float* __restrict__ Wq, const float* __restrict__ Wk,
                              const float* __restrict__ Wv, const float* __restrict__ Wo,
                              short* __restrict__ Wqkvt, short* __restrict__ Wot) {
  const int z = blockIdx.z, e = z >> 2, m = z & 3;
  const float* W = (m == 0) ? Wq : (m == 1) ? Wk : (m == 2) ? Wv : Wo;
  const float* Wb = W + (size_t)e * CH * CH;
  short* dst = (m == 3) ? (Wot + (size_t)e * CH * CH)
                        : (Wqkvt + ((size_t)e * C3H + m * CH) * CH);
  tpose_body(Wb, dst, CH, CH);
}

// fused QKV bias [E][2304]
__global__ void qkv_bias_kernel(const float* __restrict__ bq, const float* __restrict__ bk,
                                const float* __restrict__ bv, float* __restrict__ dst) {
  int i = blockIdx.x * 256 + threadIdx.x;
  if (i >= CE * C3H) return;
  int e = i / C3H, r = i % C3H;
  int m = r / CH, c = r % CH;
  const float* s = (m == 0) ? bq : (m == 1) ? bk : bv;
  dst[i] = s[e * CH + c];
}

// ---------------- big-tile GEMM: 256 x BN, BK=32, 8 waves, double-buffer ----
// out[4096,*] = act(A[4096,ldk-slice] @ Wt[e][N,ldk]^T + bias)
// 2-phase minimum recipe (T3): STAGE(next) -> ds_read -> MFMA -> vmcnt(0)+barrier.
template <int BN, int ACT, bool OB16>
__global__ __launch_bounds__(512, 2)
void gemm2_kernel(const short* __restrict__ A, const short* __restrict__ Wt,
                  const float* __restrict__ bias, const int* __restrict__ eidx,
                  char* __restrict__ out,
                  int ldk, int NT, int kSplit, int NTm,
                  size_t wtExpStride, int biasStride,
                  int outLd, size_t outKsStride) {
  constexpr int WARPS_N = BN / 64, WARPS_M = 8 / WARPS_N, WM = 256 / WARPS_M, MI = WM / 16;
  __shared__ __align__(16) short As[2][256 * 32];
  __shared__ __align__(16) short Bs[2][BN * 32];
  const int t = threadIdx.x, w = t >> 6, l = t & 63, lr = l & 15, lg = l >> 4;

  // XCD-chunked decode (grid % 8 == 0 for all launches)
  const int chunk = (int)gridDim.x >> 3;
  const int swz = ((int)blockIdx.x & 7) * chunk + ((int)blockIdx.x >> 3);
  const int nt = swz / (kSplit * NTm);
  const int r2 = swz - nt * (kSplit * NTm);
  const int ks = r2 / NTm, mt = r2 - ks * NTm;
  const int e  = eidx[mt >> 1];
  const int kBase = ks * NT * 32;

  // staging source: thread t covers LDS row (t>>2) (+128 per issue), slot t&3,
  // global col pre-swizzled: slot ^= (row>>1)&3  (row bits 1,2 = t bits 3,4)
  const int srow = t >> 2;
  const int gcol = (((t & 3) ^ ((t >> 3) & 3)) * 8);
  const short* aSrc = A + (size_t)(mt * 256 + srow) * ldk + kBase + gcol;
  const short* bSrc = Wt + (size_t)e * wtExpStride + (size_t)(nt * BN + srow) * ldk + kBase + gcol;
  const size_t issStride = (size_t)128 * ldk;

  // frag read offsets (matching swizzle on read)
  const int wrow = (w / WARPS_N) * WM, wn = (w % WARPS_N) * 64;
  const int rswz = (lg ^ ((lr >> 1) & 3)) * 8;
  int aoff[MI], boff[4];
#pragma unroll
  for (int mi = 0; mi < MI; ++mi) aoff[mi] = (wrow + mi * 16 + lr) * 32 + rswz;
#pragma unroll
  for (int ni = 0; ni < 4; ++ni)  boff[ni] = (wn + ni * 16 + lr) * 32 + rswz;

  f32x4 acc[MI][4] = {};

  auto STAGE = [&](int buf, int kt) {
    const short* as = aSrc + kt * 32;
    gload_lds16(as,             &As[buf][t * 8]);
    gload_lds16(as + issStride, &As[buf][4096 + t * 8]);
    const short* bs = bSrc + kt * 32;
    gload_lds16(bs, &Bs[buf][t * 8]);
    if (BN == 256) gload_lds16(bs + issStride, &Bs[buf][4096 + t * 8]);
  };

  STAGE(0, 0);
  VMCNT(0);
  __builtin_amdgcn_s_barrier();
  __builtin_amdgcn_sched_barrier(0);

  for (int kt = 0; kt < NT; ++kt) {
    const int buf = kt & 1;
    if (kt + 1 < NT) STAGE(buf ^ 1, kt + 1);
    bf16x8 bfr[4], af[MI];
#pragma unroll
    for (int ni = 0; ni < 4; ++ni)  bfr[ni] = *(const bf16x8*)(&Bs[buf][boff[ni]]);
#pragma unroll
    for (int mi = 0; mi < MI; ++mi) af[mi] = *(const bf16x8*)(&As[buf][aoff[mi]]);
    __builtin_amdgcn_s_setprio(1);
#pragma unroll
    for (int mi = 0; mi < MI; ++mi)
#pragma unroll
      for (int ni = 0; ni < 4; ++ni)
        acc[mi][ni] = __builtin_amdgcn_mfma_f32_16x16x32_bf16(af[mi], bfr[ni], acc[mi][ni], 0, 0, 0);
    __builtin_amdgcn_s_setprio(0);
    VMCNT(0);
    __builtin_amdgcn_s_barrier();
    __builtin_amdgcn_sched_barrier(0);
  }

  // epilogue
  float* outF = (float*)out + (size_t)ks * outKsStride;
#pragma unroll
  for (int ni = 0; ni < 4; ++ni) {
    const int col = nt * BN + wn + ni * 16 + lr;
    const float bv = bias ? bias[e * biasStride + col] : 0.0f;
#pragma unroll
    for (int mi = 0; mi < MI; ++mi) {
      const int row0 = mt * 256 + wrow + mi * 16 + lg * 4;
#pragma unroll
      for (int r = 0; r < 4; ++r) {
        float v = acc[mi][ni][r] + bv;
        if (ACT == 1) v = 0.5f * v * (1.0f + erff(v * 0.70710678118654752f));  // exact GELU
        if (OB16) ((short*)out)[(size_t)(row0 + r) * outLd + col] = f2bf(v);
        else      outF[(size_t)(row0 + r) * outLd + col] = v;
      }
    }
  }
}

// ---------------- fused attention ----------------
// Q/K/V live in fused QKV buffer, row stride 2304. ctx row stride 768.
__global__ void attn_kernel(const short* __restrict__ QKV, const float* __restrict__ mask,
                            short* __restrict__ ctx) {
  __shared__ __align__(16) short Vt[2][64 * 40];
  __shared__ __align__(16) short Pt[4][2][16 * 40];
  const int bh = blockIdx.x;
  const int b = bh / CNH, h = bh % CNH;
  const int qt = blockIdx.y;
  const int t = threadIdx.x, w = t >> 6, l = t & 63, lr = l & 15, lg = l >> 4;

  const size_t bS = (size_t)b * CS;
  const short* Qh = QKV + bS * C3H + h * CDH;
  const short* Kh = Qh + CH;
  const short* Vh = Qh + 2 * CH;
  const float* mrow = mask + bS;

  const int qrow = qt * 64 + w * 16 + lr;
  bf16x8 qa[2];
  qa[0] = *(const bf16x8*)(Qh + (size_t)qrow * C3H + lg * 8);
  qa[1] = *(const bf16x8*)(Qh + (size_t)qrow * C3H + 32 + lg * 8);

  f32x4 o[4] = {};
  float lp[4] = {0.f, 0.f, 0.f, 0.f};

  const int dh = t & 63, kg = t >> 6;
  {
    short v8[8];
#pragma unroll
    for (int j = 0; j < 8; ++j) v8[j] = Vh[(size_t)(kg * 8 + j) * C3H + dh];
    uint32_t p0 = (uint32_t)(uint16_t)v8[0] | ((uint32_t)(uint16_t)v8[1] << 16);
    uint32_t p1 = (uint32_t)(uint16_t)v8[2] | ((uint32_t)(uint16_t)v8[3] << 16);
    uint32_t p2 = (uint32_t)(uint16_t)v8[4] | ((uint32_t)(uint16_t)v8[5] << 16);
    uint32_t p3 = (uint32_t)(uint16_t)v8[6] | ((uint32_t)(uint16_t)v8[7] << 16);
    uint4 pk = {p0, p1, p2, p3};
    *(uint4*)(&Vt[0][dh * 40 + kg * 8]) = pk;
  }

  for (int tt = 0; tt < CS / 32; ++tt) {
    const int k0 = tt * 32;
    __syncthreads();

    f32x4 sacc[2] = {};
#pragma unroll
    for (int n = 0; n < 2; ++n) {
      bf16x8 kb0 = *(const bf16x8*)(Kh + (size_t)(k0 + n * 16 + lr) * C3H + lg * 8);
      bf16x8 kb1 = *(const bf16x8*)(Kh + (size_t)(k0 + n * 16 + lr) * C3H + 32 + lg * 8);
      sacc[n] = __builtin_amdgcn_mfma_f32_16x16x32_bf16(qa[0], kb0, sacc[n], 0, 0, 0);
      sacc[n] = __builtin_amdgcn_mfma_f32_16x16x32_bf16(qa[1], kb1, sacc[n], 0, 0, 0);
    }

    if (tt + 1 < CS / 32) {
      const int k1 = k0 + 32;
      short v8[8];
#pragma unroll
      for (int j = 0; j < 8; ++j) v8[j] = Vh[(size_t)(k1 + kg * 8 + j) * C3H + dh];
      uint32_t p0 = (uint32_t)(uint16_t)v8[0] | ((uint32_t)(uint16_t)v8[1] << 16);
      uint32_t p1 = (uint32_t)(uint16_t)v8[2] | ((uint32_t)(uint16_t)v8[3] << 16);
      uint32_t p2 = (uint32_t)(uint16_t)v8[4] | ((uint32_t)(uint16_t)v8[5] << 16);
      uint32_t p3 = (uint32_t)(uint16_t)v8[6] | ((uint32_t)(uint16_t)v8[7] << 16);
      uint4 pk = {p0, p1, p2, p3};
      *(uint4*)(&Vt[(tt + 1) & 1][dh * 40 + kg * 8]) = pk;
    }

    const int pb = tt & 1;
#pragma unroll
    for (int n = 0; n < 2; ++n) {
      float mv = mrow[k0 + n * 16 + lr];
#pragma unroll
      for (int r = 0; r < 4; ++r) {
        float s = sacc[n][r] * 0.125f + mv;
        float e = __expf(s);
        lp[r] += e;
        Pt[w][pb][(lg * 4 + r) * 40 + n * 16 + lr] = f2bf(e);
      }
    }

    bf16x8 pa = *(const bf16x8*)(&Pt[w][pb][lr * 40 + lg * 8]);
#pragma unroll
    for (int d = 0; d < 4; ++d) {
      bf16x8 vbf = *(const bf16x8*)(&Vt[tt & 1][(d * 16 + lr) * 40 + lg * 8]);
      o[d] = __builtin_amdgcn_mfma_f32_16x16x32_bf16(pa, vbf, o[d], 0, 0, 0);
    }
  }

#pragma unroll
  for (int r = 0; r < 4; ++r) {
    float s = lp[r];
    s += __shfl_xor(s, 1); s += __shfl_xor(s, 2);
    s += __shfl_xor(s, 4); s += __shfl_xor(s, 8);
    lp[r] = 1.0f / s;
  }
#pragma unroll
  for (int d = 0; d < 4; ++d)
#pragma unroll
    for (int r = 0; r < 4; ++r) {
      int row = qt * 64 + w * 16 + lg * 4 + r;
      ctx[(bS + row) * CH + h * CDH + d * 16 + lr] = f2bf(o[d][r] * lp[r]);
    }
}

// ---------------- residual + LayerNorm (1 wave per row) ----------------
__global__ void ln_kernel(const float* __restrict__ xin, const float* __restrict__ res,
                          const float* __restrict__ g, const float* __restrict__ bta,
                          float* __restrict__ out32, short* __restrict__ out16) {
  const int row = blockIdx.x;
  const int l = threadIdx.x;  // 64 threads
  const float* xr = xin + (size_t)row * CH;
  const float* rr = res + (size_t)row * CH;
  float4 v[3];
  float sum = 0.f, ss = 0.f;
#pragma unroll
  for (int j = 0; j < 3; ++j) {
    float4 a = *(const float4*)(xr + j * 256 + l * 4);
    float4 b = *(const float4*)(rr + j * 256 + l * 4);
    a.x += b.x; a.y += b.y; a.z += b.z; a.w += b.w;
    v[j] = a;
    sum += a.x + a.y + a.z + a.w;
    ss  += a.x * a.x + a.y * a.y + a.z * a.z + a.w * a.w;
  }
#pragma unroll
  for (int m = 1; m < 64; m <<= 1) { sum += __shfl_xor(sum, m); ss += __shfl_xor(ss, m); }
  const float mean = sum * (1.0f / CH);
  const float var  = ss * (1.0f / CH) - mean * mean;
  const float rstd = rsqrtf(var + 1e-12f);
#pragma unroll
  for (int j = 0; j < 3; ++j) {
    float4 gg = *(const float4*)(g   + j * 256 + l * 4);
    float4 bb = *(const float4*)(bta + j * 256 + l * 4);
    float4 a = v[j], y;
    y.x = (a.x - mean) * rstd * gg.x + bb.x;
    y.y = (a.y - mean) * rstd * gg.y + bb.y;
    y.z = (a.z - mean) * rstd * gg.z + bb.z;
    y.w = (a.w - mean) * rstd * gg.w + bb.w;
    *(float4*)(out32 + (size_t)row * CH + j * 256 + l * 4) = y;
    if (out16) {
      short4 o;
      o.x = f2bf(y.x); o.y = f2bf(y.y); o.z = f2bf(y.z); o.w = f2bf(y.w);
      *(short4*)(out16 + (size_t)row * CH + j * 256 + l * 4) = o;
    }
  }
}

// LN2: sums 2 split-K partials + expert bias + residual, then LayerNorm -> d_out
__global__ void ln2_kernel(const float* __restrict__ p0, const float* __restrict__ p1,
                           const float* __restrict__ res,
                           const float* __restrict__ bout, const int* __restrict__ eidx,
                           const float* __restrict__ g, const float* __restrict__ bta,
                           float* __restrict__ out) {
  const int row = blockIdx.x;
  const int l = threadIdx.x;
  const int e = eidx[row >> 9];
  const float* xr0 = p0 + (size_t)row * CH;
  const float* xr1 = p1 + (size_t)row * CH;
  const float* rr  = res + (size_t)row * CH;
  const float* bo  = bout + (size_t)e * CH;
  float4 v[3];
  float sum = 0.f, ss = 0.f;
#pragma unroll
  for (int j = 0; j < 3; ++j) {
    float4 a = *(const float4*)(xr0 + j * 256 + l * 4);
    float4 c = *(const float4*)(xr1 + j * 256 + l * 4);
    float4 b = *(const float4*)(rr + j * 256 + l * 4);
    float4 bb = *(const float4*)(bo + j * 256 + l * 4);
    a.x += c.x + b.x + bb.x; a.y += c.y + b.y + bb.y;
    a.z += c.z + b.z + bb.z; a.w += c.w + b.w + bb.w;
    v[j] = a;
    sum += a.x + a.y + a.z + a.w;
    ss  += a.x * a.x + a.y * a.y + a.z * a.z + a.w * a.w;
  }
#pragma unroll
  for (int m = 1; m < 64; m <<= 1) { sum += __shfl_xor(sum, m); ss += __shfl_xor(ss, m); }
  const float mean = sum * (1.0f / CH);
  const float var  = ss * (1.0f / CH) - mean * mean;
  const float rstd = rsqrtf(var + 1e-12f);
#pragma unroll
  for (int j = 0; j < 3; ++j) {
    float4 gg = *(const float4*)(g   + j * 256 + l * 4);
    float4 bb = *(const float4*)(bta + j * 256 + l * 4);
    float4 a = v[j], y;
    y.x = (a.x - mean) * rstd * gg.x + bb.x;
    y.y = (a.y - mean) * rstd * gg.y + bb.y;
    y.z = (a.z - mean) * rstd * gg.z + bb.z;
    y.w = (a.w - mean) * rstd * gg.w + bb.w;
    *(float4*)(out + (size_t)row * CH + j * 256 + l * 4) = y;
  }
}

// ---------------- launcher ----------------
extern "C" void kernel_launch(void* const* d_in, const int* in_sizes, int n_in,
                              void* d_out, int out_size, void* d_ws, size_t ws_size,
                              hipStream_t stream) {
  (void)in_sizes; (void)n_in; (void)out_size; (void)ws_size;
  const float* hidden = (const float*)d_in[0];
  const int*   eidx   = (const int*)d_in[1];
  const float* mask   = (const float*)d_in[2];
  const float* Wq   = (const float*)d_in[3];
  const float* bq   = (const float*)d_in[4];
  const float* Wk   = (const float*)d_in[5];
  const float* bk   = (const float*)d_in[6];
  const float* Wv   = (const float*)d_in[7];
  const float* bv   = (const float*)d_in[8];
  const float* Wo   = (const float*)d_in[9];
  const float* bo   = (const float*)d_in[10];
  const float* ln1g = (const float*)d_in[11];
  const float* ln1b = (const float*)d_in[12];
  const float* Wi   = (const float*)d_in[13];
  const float* bi   = (const float*)d_in[14];
  const float* Wout = (const float*)d_in[15];
  const float* bout = (const float*)d_in[16];
  const float* ln2g = (const float*)d_in[17];
  const float* ln2b = (const float*)d_in[18];

  char* ws = (char*)d_ws;
  size_t off = 0;
  auto alloc = [&](size_t bytes) {
    void* p = ws + off;
    off += (bytes + 255) & ~(size_t)255;
    return p;
  };
  const size_t M = (size_t)CB * CS;                    // 4096 rows
  short* Xb    = (short*)alloc(M * CH * 2);            // 6.3 MB; later reused as x1b
  char*  Rbig  = (char*)alloc(M * CFF * 2);            // 25.2 MB: QKVb then hmid
  char*  Rcx   = (char*)alloc(M * CH * 4);             // 12.6 MB: ctxb then x1
  float* ffnp  = (float*)alloc(2 * M * CH * 4);        // 25.2 MB split-K partials
  float* qkvbias = (float*)alloc(CE * C3H * 4);
  short* Wqkvt = (short*)alloc((size_t)CE * C3H * CH * 2);   // 14.2 MB; tail reused as attn_out
  short* Wot   = (short*)alloc((size_t)CE * CH * CH * 2);
  short* Wit   = (short*)alloc((size_t)CE * CH * CFF * 2);
  short* Wo2t  = (short*)alloc((size_t)CE * CFF * CH * 2);
  // aliases (disjoint lifetimes)
  short* QKVb     = (short*)Rbig;        // after QKV gemm, until attn
  short* hmid     = (short*)Rbig;        // FFN1 out (after attn)
  short* ctxb     = (short*)Rcx;         // attn out, until O-proj
  float* x1       = (float*)Rcx;         // LN1 out (after O-proj)
  short* x1b      = Xb;                  // LN1 bf16 out (Xb dead after QKV)
  float* attn_out = (float*)Wqkvt;       // O-proj out (Wqkvt dead after QKV), 12.6<=14.2 MB

  // 1. prep
  const int n4 = (int)(M * CH / 4);
  cvt_bf16_kernel<<<(n4 + 255) / 256, 256, 0, stream>>>(hidden, Xb, n4);
  tpose4_kernel<<<dim3(CH / 64, CH / 64, 4 * CE), 256, 0, stream>>>(Wq, Wk, Wv, Wo, Wqkvt, Wot);
  tpose_cvt_kernel<<<dim3(CFF / 64, CH / 64, CE), 256, 0, stream>>>(Wi, Wit, CH, CFF);
  tpose_cvt_kernel<<<dim3(CH / 64, CFF / 64, CE), 256, 0, stream>>>(Wout, Wo2t, CFF, CH);
  qkv_bias_kernel<<<(CE * C3H + 255) / 256, 256, 0, stream>>>(bq, bk, bv, qkvbias);

  // 2. QKV fused GEMM: [4096,768] x [2304,768]^T -> [4096,2304] bf16
  gemm2_kernel<256, 0, true><<<(C3H / 256) * 16, 512, 0, stream>>>(
      Xb, Wqkvt, qkvbias, eidx, (char*)QKVb,
      CH, CH / 32, 1, 16, (size_t)C3H * CH, C3H, C3H, 0);
  // 3. attention
  attn_kernel<<<dim3(CB * CNH, CS / 64), 256, 0, stream>>>(QKVb, mask, ctxb);
  // 4. O projection -> f32
  gemm2_kernel<128, 0, false><<<(CH / 128) * 16, 512, 0, stream>>>(
      ctxb, Wot, bo, eidx, (char*)attn_out,
      CH, CH / 32, 1, 16, (size_t)CH * CH, CH, CH, 0);
  // 5. LN1
  ln_kernel<<<(int)M, 64, 0, stream>>>(attn_out, hidden, ln1g, ln1b, x1, x1b);
  // 6. FFN intermediate + GELU -> bf16
  gemm2_kernel<256, 1, true><<<(CFF / 256) * 16, 512, 0, stream>>>(
      x1b, Wit, bi, eidx, (char*)hmid,
      CH, CH / 32, 1, 16, (size_t)CH * CFF, CFF, CFF, 0);
  // 7. FFN output, split-K=2, raw partials (bias folded into LN2)
  gemm2_kernel<128, 0, false><<<(CH / 128) * 16 * 2, 512, 0, stream>>>(
      hmid, Wo2t, nullptr, eidx, (char*)ffnp,
      CFF, CFF / 2 / 32, 2, 16, (size_t)CFF * CH, CH, CH, M * CH);
  // 8. LN2 (partial-sum + bias + residual) -> d_out
  ln2_kernel<<<(int)M, 64, 0, stream>>>(ffnp, ffnp + M * CH, x1, bout, eidx,
                                        ln2g, ln2b, (float*)d_out);
}

// Round 4
// 220.428 us; speedup vs baseline: 1.0912x; 1.0912x over previous
//
#include <hip/hip_runtime.h>
#include <cstdint>
#include <cstddef>

// ---------------- problem constants ----------------
constexpr int CB  = 8;     // batch
constexpr int CS  = 512;   // seq len
constexpr int CH  = 768;   // hidden
constexpr int CNH = 12;    // heads
constexpr int CDH = 64;    // head dim
constexpr int CFF = 3072;  // ffn dim
constexpr int CE  = 4;     // experts
constexpr int C3H = 3 * CH;  // 2304 fused QKV width

using f32x4  = __attribute__((ext_vector_type(4))) float;
using bf16x8 = __attribute__((ext_vector_type(8))) short;

__device__ __forceinline__ short f2bf(float x) {
  union { float f; uint32_t u; } v; v.f = x;
  return (short)((v.u + 0x7fffu + ((v.u >> 16) & 1u)) >> 16);  // RNE
}

__device__ __forceinline__ void gload_lds16(const void* g, void* l) {
  __builtin_amdgcn_global_load_lds((const __attribute__((address_space(1))) void*)g,
                                   (__attribute__((address_space(3))) void*)l,
                                   16, 0, 0);
}

#define VMCNT(n)  asm volatile("s_waitcnt vmcnt(" #n ")" ::: "memory")

// ---------------- fp32 -> bf16 elementwise ----------------
__global__ void cvt_bf16_kernel(const float* __restrict__ in, short* __restrict__ out, int n4) {
  int i = blockIdx.x * blockDim.x + threadIdx.x;
  if (i < n4) {
    float4 v = ((const float4*)in)[i];
    short4 o;
    o.x = f2bf(v.x); o.y = f2bf(v.y); o.z = f2bf(v.z); o.w = f2bf(v.w);
    ((short4*)out)[i] = o;
  }
}

// ---------------- transpose+convert: W [K,N] f32 -> Wt [N,K] bf16 ------
__device__ __forceinline__ bool expert_used(const int* __restrict__ eidx, int e) {
  bool u = false;
#pragma unroll
  for (int s = 0; s < CB; ++s) u |= (eidx[s] == e);
  return u;
}

__device__ __forceinline__ void tpose_body(const float* __restrict__ Wb,
                                           short* __restrict__ Wtb, int K, int N) {
  __shared__ __align__(16) short Ts[64 * 68];
  const int n0 = blockIdx.x * 64, k0 = blockIdx.y * 64;
  const int t  = threadIdx.x;
  const int tn = t & 15, tk = t >> 4;
#pragma unroll
  for (int p = 0; p < 4; ++p) {
    int k = k0 + p * 16 + tk;
    float4 v = *(const float4*)(Wb + (size_t)k * N + n0 + tn * 4);
#pragma unroll
    for (int j = 0; j < 4; ++j)
      Ts[(tn * 4 + j) * 68 + p * 16 + tk] = f2bf(((const float*)&v)[j]);
  }
  __syncthreads();
#pragma unroll
  for (int p = 0; p < 4; ++p) {
    int n = n0 + p * 16 + tk;
    uint2 o = *(const uint2*)(Ts + (p * 16 + tk) * 68 + tn * 4);
    *(uint2*)(Wtb + (size_t)n * K + k0 + tn * 4) = o;
  }
}

__global__ void tpose_cvt_kernel(const float* __restrict__ W, short* __restrict__ Wt,
                                 const int* __restrict__ eidx, int K, int N) {
  const int e = blockIdx.z;
  if (!expert_used(eidx, e)) return;
  tpose_body(W + (size_t)e * K * N, Wt + (size_t)e * K * N, K, N);
}

// fused: z = e*4 + m; m in {0,1,2}: Wq/Wk/Wv -> Wqkvt; m==3: Wo -> Wot
__global__ void tpose4_kernel(const float* __restrict__ Wq, const float* __restrict__ Wk,
                              const float* __restrict__ Wv, const float* __restrict__ Wo,
                              const int* __restrict__ eidx,
                              short* __restrict__ Wqkvt, short* __restrict__ Wot) {
  const int z = blockIdx.z, e = z >> 2, m = z & 3;
  if (!expert_used(eidx, e)) return;
  const float* W = (m == 0) ? Wq : (m == 1) ? Wk : (m == 2) ? Wv : Wo;
  const float* Wb = W + (size_t)e * CH * CH;
  short* dst = (m == 3) ? (Wot + (size_t)e * CH * CH)
                        : (Wqkvt + ((size_t)e * C3H + m * CH) * CH);
  tpose_body(Wb, dst, CH, CH);
}

// fused QKV bias [E][2304]
__global__ void qkv_bias_kernel(const float* __restrict__ bq, const float* __restrict__ bk,
                                const float* __restrict__ bv, float* __restrict__ dst) {
  int i = blockIdx.x * 256 + threadIdx.x;
  if (i >= CE * C3H) return;
  int e = i / C3H, r = i % C3H;
  int m = r / CH, c = r % CH;
  const float* s = (m == 0) ? bq : (m == 1) ? bk : bv;
  dst[i] = s[e * CH + c];
}

// ---------------- GEMM: BM x BN tile, BK=32, TPB/64 waves, double-buffer ----
// 2-phase: STAGE(next) -> ds_read -> MFMA -> vmcnt(0)+barrier. T2 swizzle, T5.
// Block order: expert-sorted j (M-tiles grouped by expert), nt fastest, so each
// XCD chunk = one expert x few A-tiles x all nt -> staging stays L2-resident.
template <int BM, int BN, int TPB, int K, int NTN, int KSPLIT, int ACT, bool OB16>
__global__ __launch_bounds__(TPB, (TPB == 512 ? 2 : 3))
void gemm3_kernel(const short* __restrict__ A, const short* __restrict__ Wt,
                  const float* __restrict__ bias, const int* __restrict__ eidx,
                  char* __restrict__ out,
                  size_t wtExpStride, int biasStride, int outLd, size_t outKsStride) {
  constexpr int WAVES = TPB / 64;
  constexpr int WARPS_N = BN / 64, WARPS_M = WAVES / WARPS_N;
  constexpr int WM = BM / WARPS_M, MI = WM / 16;
  constexpr int NT = K / KSPLIT / 32;      // K-steps per split
  constexpr int JC = 4096 / BM;            // total M-tiles
  constexpr int MTS = CS / BM;             // M-tiles per sample
  __shared__ __align__(16) short As[2][BM * 32];
  __shared__ __align__(16) short Bs[2][BN * 32];
  const int t = threadIdx.x, w = t >> 6, l = t & 63, lr = l & 15, lg = l >> 4;

  // ---- expert-sorted work decode (uniform, register-only) ----
  int exv[CB];
#pragma unroll
  for (int s = 0; s < CB; ++s) exv[s] = eidx[s];
  uint32_t epack = 0;
#pragma unroll
  for (int s = 0; s < CB; ++s) epack |= (uint32_t)exv[s] << (2 * s);
  int c0 = 0, c1 = 0, c2 = 0, c3 = 0;
#pragma unroll
  for (int s = 0; s < CB; ++s) {
    c0 += (exv[s] == 0); c1 += (exv[s] == 1); c2 += (exv[s] == 2); c3 += (exv[s] == 3);
  }
  int p0 = 0, p1 = c0, p2 = c0 + c1, p3 = c0 + c1 + c2;
  uint32_t sortedPack = 0;
#pragma unroll
  for (int s = 0; s < CB; ++s) {
    int e = exv[s];
    int p = (e == 0) ? p0 : (e == 1) ? p1 : (e == 2) ? p2 : p3;
    sortedPack |= (uint32_t)s << (4 * p);
    p0 += (e == 0); p1 += (e == 1); p2 += (e == 2); p3 += (e == 3);
  }
  // XCD-chunked linear work id
  const int chunk = (int)gridDim.x >> 3;
  const int W_ = ((int)blockIdx.x & 7) * chunk + ((int)blockIdx.x >> 3);
  const int ks = W_ / (JC * NTN);
  const int r1 = W_ - ks * (JC * NTN);
  const int j  = r1 / NTN, nt = r1 - j * NTN;
  const int sample = (int)((sortedPack >> (4 * (j / MTS))) & 7);
  const int jj = j % MTS;
  const int e  = (int)((epack >> (2 * sample)) & 3);
  const int mrow0 = sample * CS + jj * BM;     // global row base
  const int kBase = ks * NT * 32;

  // ---- staging addresses (linear LDS dest, pre-swizzled global col) ----
  const int srow = t >> 2;                           // [0, TPB/4)
  const int gcol = (((t & 3) ^ ((t >> 3) & 3)) * 8);
  const short* aSrc = A + (size_t)(mrow0 + srow) * K + kBase + gcol;
  const short* bSrc = Wt + (size_t)e * wtExpStride + (size_t)(nt * BN + srow) * K + kBase + gcol;
  constexpr int ROWS_PER_ISS = TPB / 4;              // rows covered per issue
  const size_t issStride = (size_t)ROWS_PER_ISS * K;

  // ---- frag read offsets (matching swizzle) ----
  const int wrow = (w / WARPS_N) * WM, wn = (w % WARPS_N) * 64;
  const int rswz = (lg ^ ((lr >> 1) & 3)) * 8;
  int aoff[MI], boff[4];
#pragma unroll
  for (int mi = 0; mi < MI; ++mi) aoff[mi] = (wrow + mi * 16 + lr) * 32 + rswz;
#pragma unroll
  for (int ni = 0; ni < 4; ++ni)  boff[ni] = (wn + ni * 16 + lr) * 32 + rswz;

  f32x4 acc[MI][4] = {};

  auto STAGE = [&](int buf, int kt) {
    const short* as = aSrc + kt * 32;
#pragma unroll
    for (int i = 0; i < BM / ROWS_PER_ISS; ++i)
      gload_lds16(as + i * issStride, &As[buf][i * TPB * 8 + t * 8]);
    const short* bs = bSrc + kt * 32;
#pragma unroll
    for (int i = 0; i < BN / ROWS_PER_ISS; ++i)
      gload_lds16(bs + i * issStride, &Bs[buf][i * TPB * 8 + t * 8]);
  };

  STAGE(0, 0);
  VMCNT(0);
  __builtin_amdgcn_s_barrier();
  __builtin_amdgcn_sched_barrier(0);

  for (int kt = 0; kt < NT; ++kt) {
    const int buf = kt & 1;
    if (kt + 1 < NT) STAGE(buf ^ 1, kt + 1);
    bf16x8 bfr[4], af[MI];
#pragma unroll
    for (int ni = 0; ni < 4; ++ni)  bfr[ni] = *(const bf16x8*)(&Bs[buf][boff[ni]]);
#pragma unroll
    for (int mi = 0; mi < MI; ++mi) af[mi] = *(const bf16x8*)(&As[buf][aoff[mi]]);
    __builtin_amdgcn_s_setprio(1);
#pragma unroll
    for (int mi = 0; mi < MI; ++mi)
#pragma unroll
      for (int ni = 0; ni < 4; ++ni)
        acc[mi][ni] = __builtin_amdgcn_mfma_f32_16x16x32_bf16(af[mi], bfr[ni], acc[mi][ni], 0, 0, 0);
    __builtin_amdgcn_s_setprio(0);
    VMCNT(0);
    __builtin_amdgcn_s_barrier();
    __builtin_amdgcn_sched_barrier(0);
  }

  // epilogue
  float* outF = (float*)out + (size_t)ks * outKsStride;
#pragma unroll
  for (int ni = 0; ni < 4; ++ni) {
    const int col = nt * BN + wn + ni * 16 + lr;
    const float bv = bias ? bias[e * biasStride + col] : 0.0f;
#pragma unroll
    for (int mi = 0; mi < MI; ++mi) {
      const int row0 = mrow0 + wrow + mi * 16 + lg * 4;
#pragma unroll
      for (int r = 0; r < 4; ++r) {
        float v = acc[mi][ni][r] + bv;
        if (ACT == 1) v = 0.5f * v * (1.0f + erff(v * 0.70710678118654752f));  // exact GELU
        if (OB16) ((short*)out)[(size_t)(row0 + r) * outLd + col] = f2bf(v);
        else      outF[(size_t)(row0 + r) * outLd + col] = v;
      }
    }
  }
}

// ---------------- fused attention ----------------
__global__ void attn_kernel(const short* __restrict__ QKV, const float* __restrict__ mask,
                            short* __restrict__ ctx) {
  __shared__ __align__(16) short Vt[2][64 * 40];
  __shared__ __align__(16) short Pt[4][2][16 * 40];
  const int bh = blockIdx.x;
  const int b = bh / CNH, h = bh % CNH;
  const int qt = blockIdx.y;
  const int t = threadIdx.x, w = t >> 6, l = t & 63, lr = l & 15, lg = l >> 4;

  const size_t bS = (size_t)b * CS;
  const short* Qh = QKV + bS * C3H + h * CDH;
  const short* Kh = Qh + CH;
  const short* Vh = Qh + 2 * CH;
  const float* mrow = mask + bS;

  const int qrow = qt * 64 + w * 16 + lr;
  bf16x8 qa[2];
  qa[0] = *(const bf16x8*)(Qh + (size_t)qrow * C3H + lg * 8);
  qa[1] = *(const bf16x8*)(Qh + (size_t)qrow * C3H + 32 + lg * 8);

  f32x4 o[4] = {};
  float lp[4] = {0.f, 0.f, 0.f, 0.f};

  const int dh = t & 63, kg = t >> 6;
  {
    short v8[8];
#pragma unroll
    for (int j = 0; j < 8; ++j) v8[j] = Vh[(size_t)(kg * 8 + j) * C3H + dh];
    uint32_t p0 = (uint32_t)(uint16_t)v8[0] | ((uint32_t)(uint16_t)v8[1] << 16);
    uint32_t p1 = (uint32_t)(uint16_t)v8[2] | ((uint32_t)(uint16_t)v8[3] << 16);
    uint32_t p2 = (uint32_t)(uint16_t)v8[4] | ((uint32_t)(uint16_t)v8[5] << 16);
    uint32_t p3 = (uint32_t)(uint16_t)v8[6] | ((uint32_t)(uint16_t)v8[7] << 16);
    uint4 pk = {p0, p1, p2, p3};
    *(uint4*)(&Vt[0][dh * 40 + kg * 8]) = pk;
  }

  for (int tt = 0; tt < CS / 32; ++tt) {
    const int k0 = tt * 32;
    __syncthreads();

    f32x4 sacc[2] = {};
#pragma unroll
    for (int n = 0; n < 2; ++n) {
      bf16x8 kb0 = *(const bf16x8*)(Kh + (size_t)(k0 + n * 16 + lr) * C3H + lg * 8);
      bf16x8 kb1 = *(const bf16x8*)(Kh + (size_t)(k0 + n * 16 + lr) * C3H + 32 + lg * 8);
      sacc[n] = __builtin_amdgcn_mfma_f32_16x16x32_bf16(qa[0], kb0, sacc[n], 0, 0, 0);
      sacc[n] = __builtin_amdgcn_mfma_f32_16x16x32_bf16(qa[1], kb1, sacc[n], 0, 0, 0);
    }

    if (tt + 1 < CS / 32) {
      const int k1 = k0 + 32;
      short v8[8];
#pragma unroll
      for (int j = 0; j < 8; ++j) v8[j] = Vh[(size_t)(k1 + kg * 8 + j) * C3H + dh];
      uint32_t p0 = (uint32_t)(uint16_t)v8[0] | ((uint32_t)(uint16_t)v8[1] << 16);
      uint32_t p1 = (uint32_t)(uint16_t)v8[2] | ((uint32_t)(uint16_t)v8[3] << 16);
      uint32_t p2 = (uint32_t)(uint16_t)v8[4] | ((uint32_t)(uint16_t)v8[5] << 16);
      uint32_t p3 = (uint32_t)(uint16_t)v8[6] | ((uint32_t)(uint16_t)v8[7] << 16);
      uint4 pk = {p0, p1, p2, p3};
      *(uint4*)(&Vt[(tt + 1) & 1][dh * 40 + kg * 8]) = pk;
    }

    const int pb = tt & 1;
#pragma unroll
    for (int n = 0; n < 2; ++n) {
      float mv = mrow[k0 + n * 16 + lr];
#pragma unroll
      for (int r = 0; r < 4; ++r) {
        float s = sacc[n][r] * 0.125f + mv;
        float e = __expf(s);
        lp[r] += e;
        Pt[w][pb][(lg * 4 + r) * 40 + n * 16 + lr] = f2bf(e);
      }
    }

    bf16x8 pa = *(const bf16x8*)(&Pt[w][pb][lr * 40 + lg * 8]);
#pragma unroll
    for (int d = 0; d < 4; ++d) {
      bf16x8 vbf = *(const bf16x8*)(&Vt[tt & 1][(d * 16 + lr) * 40 + lg * 8]);
      o[d] = __builtin_amdgcn_mfma_f32_16x16x32_bf16(pa, vbf, o[d], 0, 0, 0);
    }
  }

#pragma unroll
  for (int r = 0; r < 4; ++r) {
    float s = lp[r];
    s += __shfl_xor(s, 1); s += __shfl_xor(s, 2);
    s += __shfl_xor(s, 4); s += __shfl_xor(s, 8);
    lp[r] = 1.0f / s;
  }
#pragma unroll
  for (int d = 0; d < 4; ++d)
#pragma unroll
    for (int r = 0; r < 4; ++r) {
      int row = qt * 64 + w * 16 + lg * 4 + r;
      ctx[(bS + row) * CH + h * CDH + d * 16 + lr] = f2bf(o[d][r] * lp[r]);
    }
}

// ---------------- residual + LayerNorm (1 wave per row) ----------------
__global__ void ln_kernel(const float* __restrict__ xin, const float* __restrict__ res,
                          const float* __restrict__ g, const float* __restrict__ bta,
                          float* __restrict__ out32, short* __restrict__ out16) {
  const int row = blockIdx.x;
  const int l = threadIdx.x;
  const float* xr = xin + (size_t)row * CH;
  const float* rr = res + (size_t)row * CH;
  float4 v[3];
  float sum = 0.f, ss = 0.f;
#pragma unroll
  for (int j = 0; j < 3; ++j) {
    float4 a = *(const float4*)(xr + j * 256 + l * 4);
    float4 b = *(const float4*)(rr + j * 256 + l * 4);
    a.x += b.x; a.y += b.y; a.z += b.z; a.w += b.w;
    v[j] = a;
    sum += a.x + a.y + a.z + a.w;
    ss  += a.x * a.x + a.y * a.y + a.z * a.z + a.w * a.w;
  }
#pragma unroll
  for (int m = 1; m < 64; m <<= 1) { sum += __shfl_xor(sum, m); ss += __shfl_xor(ss, m); }
  const float mean = sum * (1.0f / CH);
  const float var  = ss * (1.0f / CH) - mean * mean;
  const float rstd = rsqrtf(var + 1e-12f);
#pragma unroll
  for (int j = 0; j < 3; ++j) {
    float4 gg = *(const float4*)(g   + j * 256 + l * 4);
    float4 bb = *(const float4*)(bta + j * 256 + l * 4);
    float4 a = v[j], y;
    y.x = (a.x - mean) * rstd * gg.x + bb.x;
    y.y = (a.y - mean) * rstd * gg.y + bb.y;
    y.z = (a.z - mean) * rstd * gg.z + bb.z;
    y.w = (a.w - mean) * rstd * gg.w + bb.w;
    *(float4*)(out32 + (size_t)row * CH + j * 256 + l * 4) = y;
    if (out16) {
      short4 o;
      o.x = f2bf(y.x); o.y = f2bf(y.y); o.z = f2bf(y.z); o.w = f2bf(y.w);
      *(short4*)(out16 + (size_t)row * CH + j * 256 + l * 4) = o;
    }
  }
}

// LN2: sums 2 split-K partials + expert bias + residual, then LayerNorm -> d_out
__global__ void ln2_kernel(const float* __restrict__ p0, const float* __restrict__ p1,
                           const float* __restrict__ res,
                           const float* __restrict__ bout, const int* __restrict__ eidx,
                           const float* __restrict__ g, const float* __restrict__ bta,
                           float* __restrict__ out) {
  const int row = blockIdx.x;
  const int l = threadIdx.x;
  const int e = eidx[row >> 9];
  const float* xr0 = p0 + (size_t)row * CH;
  const float* xr1 = p1 + (size_t)row * CH;
  const float* rr  = res + (size_t)row * CH;
  const float* bo  = bout + (size_t)e * CH;
  float4 v[3];
  float sum = 0.f, ss = 0.f;
#pragma unroll
  for (int j = 0; j < 3; ++j) {
    float4 a = *(const float4*)(xr0 + j * 256 + l * 4);
    float4 c = *(const float4*)(xr1 + j * 256 + l * 4);
    float4 b = *(const float4*)(rr + j * 256 + l * 4);
    float4 bb = *(const float4*)(bo + j * 256 + l * 4);
    a.x += c.x + b.x + bb.x; a.y += c.y + b.y + bb.y;
    a.z += c.z + b.z + bb.z; a.w += c.w + b.w + bb.w;
    v[j] = a;
    sum += a.x + a.y + a.z + a.w;
    ss  += a.x * a.x + a.y * a.y + a.z * a.z + a.w * a.w;
  }
#pragma unroll
  for (int m = 1; m < 64; m <<= 1) { sum += __shfl_xor(sum, m); ss += __shfl_xor(ss, m); }
  const float mean = sum * (1.0f / CH);
  const float var  = ss * (1.0f / CH) - mean * mean;
  const float rstd = rsqrtf(var + 1e-12f);
#pragma unroll
  for (int j = 0; j < 3; ++j) {
    float4 gg = *(const float4*)(g   + j * 256 + l * 4);
    float4 bb = *(const float4*)(bta + j * 256 + l * 4);
    float4 a = v[j], y;
    y.x = (a.x - mean) * rstd * gg.x + bb.x;
    y.y = (a.y - mean) * rstd * gg.y + bb.y;
    y.z = (a.z - mean) * rstd * gg.z + bb.z;
    y.w = (a.w - mean) * rstd * gg.w + bb.w;
    *(float4*)(out + (size_t)row * CH + j * 256 + l * 4) = y;
  }
}

// ---------------- launcher ----------------
extern "C" void kernel_launch(void* const* d_in, const int* in_sizes, int n_in,
                              void* d_out, int out_size, void* d_ws, size_t ws_size,
                              hipStream_t stream) {
  (void)in_sizes; (void)n_in; (void)out_size; (void)ws_size;
  const float* hidden = (const float*)d_in[0];
  const int*   eidx   = (const int*)d_in[1];
  const float* mask   = (const float*)d_in[2];
  const float* Wq   = (const float*)d_in[3];
  const float* bq   = (const float*)d_in[4];
  const float* Wk   = (const float*)d_in[5];
  const float* bk   = (const float*)d_in[6];
  const float* Wv   = (const float*)d_in[7];
  const float* bv   = (const float*)d_in[8];
  const float* Wo   = (const float*)d_in[9];
  const float* bo   = (const float*)d_in[10];
  const float* ln1g = (const float*)d_in[11];
  const float* ln1b = (const float*)d_in[12];
  const float* Wi   = (const float*)d_in[13];
  const float* bi   = (const float*)d_in[14];
  const float* Wout = (const float*)d_in[15];
  const float* bout = (const float*)d_in[16];
  const float* ln2g = (const float*)d_in[17];
  const float* ln2b = (const float*)d_in[18];

  char* ws = (char*)d_ws;
  size_t off = 0;
  auto alloc = [&](size_t bytes) {
    void* p = ws + off;
    off += (bytes + 255) & ~(size_t)255;
    return p;
  };
  const size_t M = (size_t)CB * CS;                    // 4096 rows
  short* Xb    = (short*)alloc(M * CH * 2);            // 6.3 MB; later reused as x1b
  char*  Rbig  = (char*)alloc(M * CFF * 2);            // 25.2 MB: QKVb then hmid
  char*  Rcx   = (char*)alloc(M * CH * 4);             // 12.6 MB: ctxb then x1
  float* ffnp  = (float*)alloc(2 * M * CH * 4);        // 25.2 MB split-K partials
  float* qkvbias = (float*)alloc(CE * C3H * 4);
  short* Wqkvt = (short*)alloc((size_t)CE * C3H * CH * 2);   // 14.2 MB; reused as attn_out
  short* Wot   = (short*)alloc((size_t)CE * CH * CH * 2);
  short* Wit   = (short*)alloc((size_t)CE * CH * CFF * 2);
  short* Wo2t  = (short*)alloc((size_t)CE * CFF * CH * 2);
  short* QKVb     = (short*)Rbig;
  short* hmid     = (short*)Rbig;
  short* ctxb     = (short*)Rcx;
  float* x1       = (float*)Rcx;
  short* x1b      = Xb;
  float* attn_out = (float*)Wqkvt;

  // 1. prep
  const int n4 = (int)(M * CH / 4);
  cvt_bf16_kernel<<<(n4 + 255) / 256, 256, 0, stream>>>(hidden, Xb, n4);
  tpose4_kernel<<<dim3(CH / 64, CH / 64, 4 * CE), 256, 0, stream>>>(Wq, Wk, Wv, Wo, eidx, Wqkvt, Wot);
  tpose_cvt_kernel<<<dim3(CFF / 64, CH / 64, CE), 256, 0, stream>>>(Wi, Wit, eidx, CH, CFF);
  tpose_cvt_kernel<<<dim3(CH / 64, CFF / 64, CE), 256, 0, stream>>>(Wout, Wo2t, eidx, CFF, CH);
  qkv_bias_kernel<<<(CE * C3H + 255) / 256, 256, 0, stream>>>(bq, bk, bv, qkvbias);

  // 2. QKV fused GEMM: 256x256, NTN=9 -> grid 144
  gemm3_kernel<256, 256, 512, CH, 9, 1, 0, true><<<144, 512, 0, stream>>>(
      Xb, Wqkvt, qkvbias, eidx, (char*)QKVb, (size_t)C3H * CH, C3H, C3H, 0);
  // 3. attention
  attn_kernel<<<dim3(CB * CNH, CS / 64), 256, 0, stream>>>(QKVb, mask, ctxb);
  // 4. O projection: 128x128, NTN=6 -> grid 192
  gemm3_kernel<128, 128, 256, CH, 6, 1, 0, false><<<192, 256, 0, stream>>>(
      ctxb, Wot, bo, eidx, (char*)attn_out, (size_t)CH * CH, CH, CH, 0);
  // 5. LN1
  ln_kernel<<<(int)M, 64, 0, stream>>>(attn_out, hidden, ln1g, ln1b, x1, x1b);
  // 6. FFN intermediate + GELU: 256x256, NTN=12 -> grid 192
  gemm3_kernel<256, 256, 512, CH, 12, 1, 1, true><<<192, 512, 0, stream>>>(
      x1b, Wit, bi, eidx, (char*)hmid, (size_t)CH * CFF, CFF, CFF, 0);
  // 7. FFN output: 128x128, split-K=2 (ks outermost), NTN=6 -> grid 384
  gemm3_kernel<128, 128, 256, CFF, 6, 2, 0, false><<<384, 256, 0, stream>>>(
      hmid, Wo2t, nullptr, eidx, (char*)ffnp, (size_t)CFF * CH, CH, CH, M * CH);
  // 8. LN2
  ln2_kernel<<<(int)M, 64, 0, stream>>>(ffnp, ffnp + M * CH, x1, bout, eidx,
                                        ln2g, ln2b, (float*)d_out);
}

// Round 5
// 201.408 us; speedup vs baseline: 1.1942x; 1.0944x over previous
//
#include <hip/hip_runtime.h>
#include <cstdint>
#include <cstddef>

// ---------------- problem constants ----------------
constexpr int CB  = 8;     // batch
constexpr int CS  = 512;   // seq len
constexpr int CH  = 768;   // hidden
constexpr int CNH = 12;    // heads
constexpr int CDH = 64;    // head dim
constexpr int CFF = 3072;  // ffn dim
constexpr int CE  = 4;     // experts
constexpr int C3H = 3 * CH;  // 2304 fused QKV width

using f32x4  = __attribute__((ext_vector_type(4))) float;
using bf16x8 = __attribute__((ext_vector_type(8))) short;

__device__ __forceinline__ short f2bf(float x) {
  union { float f; uint32_t u; } v; v.f = x;
  return (short)((v.u + 0x7fffu + ((v.u >> 16) & 1u)) >> 16);  // RNE
}

__device__ __forceinline__ void gload_lds16(const void* g, void* l) {
  __builtin_amdgcn_global_load_lds((const __attribute__((address_space(1))) void*)g,
                                   (__attribute__((address_space(3))) void*)l,
                                   16, 0, 0);
}

#define VMCNT(n)  asm volatile("s_waitcnt vmcnt(" #n ")" ::: "memory")
#define SCHEDB()  __builtin_amdgcn_sched_barrier(0)

// ---------------- fp32 -> bf16 elementwise ----------------
__global__ void cvt_bf16_kernel(const float* __restrict__ in, short* __restrict__ out, int n4) {
  int i = blockIdx.x * blockDim.x + threadIdx.x;
  if (i < n4) {
    float4 v = ((const float4*)in)[i];
    short4 o;
    o.x = f2bf(v.x); o.y = f2bf(v.y); o.z = f2bf(v.z); o.w = f2bf(v.w);
    ((short4*)out)[i] = o;
  }
}

// ---------------- transpose+convert: W [K,N] f32 -> Wt [N,K] bf16 ------
__device__ __forceinline__ bool expert_used(const int* __restrict__ eidx, int e) {
  bool u = false;
#pragma unroll
  for (int s = 0; s < CB; ++s) u |= (eidx[s] == e);
  return u;
}

__device__ __forceinline__ void tpose_body(const float* __restrict__ Wb,
                                           short* __restrict__ Wtb, int K, int N) {
  __shared__ __align__(16) short Ts[64 * 68];
  const int n0 = blockIdx.x * 64, k0 = blockIdx.y * 64;
  const int t  = threadIdx.x;
  const int tn = t & 15, tk = t >> 4;
#pragma unroll
  for (int p = 0; p < 4; ++p) {
    int k = k0 + p * 16 + tk;
    float4 v = *(const float4*)(Wb + (size_t)k * N + n0 + tn * 4);
#pragma unroll
    for (int j = 0; j < 4; ++j)
      Ts[(tn * 4 + j) * 68 + p * 16 + tk] = f2bf(((const float*)&v)[j]);
  }
  __syncthreads();
#pragma unroll
  for (int p = 0; p < 4; ++p) {
    int n = n0 + p * 16 + tk;
    uint2 o = *(const uint2*)(Ts + (p * 16 + tk) * 68 + tn * 4);
    *(uint2*)(Wtb + (size_t)n * K + k0 + tn * 4) = o;
  }
}

__global__ void tpose_cvt_kernel(const float* __restrict__ W, short* __restrict__ Wt,
                                 const int* __restrict__ eidx, int K, int N) {
  const int e = blockIdx.z;
  if (!expert_used(eidx, e)) return;
  tpose_body(W + (size_t)e * K * N, Wt + (size_t)e * K * N, K, N);
}

// fused: z = e*4 + m; m in {0,1,2}: Wq/Wk/Wv -> Wqkvt; m==3: Wo -> Wot
__global__ void tpose4_kernel(const float* __restrict__ Wq, const float* __restrict__ Wk,
                              const float* __restrict__ Wv, const float* __restrict__ Wo,
                              const int* __restrict__ eidx,
                              short* __restrict__ Wqkvt, short* __restrict__ Wot) {
  const int z = blockIdx.z, e = z >> 2, m = z & 3;
  if (!expert_used(eidx, e)) return;
  const float* W = (m == 0) ? Wq : (m == 1) ? Wk : (m == 2) ? Wv : Wo;
  const float* Wb = W + (size_t)e * CH * CH;
  short* dst = (m == 3) ? (Wot + (size_t)e * CH * CH)
                        : (Wqkvt + ((size_t)e * C3H + m * CH) * CH);
  tpose_body(Wb, dst, CH, CH);
}

// fused QKV bias [E][2304]
__global__ void qkv_bias_kernel(const float* __restrict__ bq, const float* __restrict__ bk,
                                const float* __restrict__ bv, float* __restrict__ dst) {
  int i = blockIdx.x * 256 + threadIdx.x;
  if (i >= CE * C3H) return;
  int e = i / C3H, r = i % C3H;
  int m = r / CH, c = r % CH;
  const float* s = (m == 0) ? bq : (m == 1) ? bk : bv;
  dst[i] = s[e * CH + c];
}

// ---------------- GEMM: BM x BN tile, BK=64, double-buffer, counted vmcnt ---
// Per K-tile: STAGE(next, 8 loads/thread) -> vmcnt(8) -> barrier ->
//   ds_read(24) + 64 MFMA (compiler lgkmcnt) -> barrier.  Never drains vmcnt
// to 0 in steady state (T4).  LDS rows are 128B: XOR swizzle byte^=(row&7)<<4
// applied on BOTH stage-source and read (rule #21) -> balanced banks.
// Expert-sorted M-tiles + XCD-chunked decode keep staging L2-resident.
template <int BM, int BN, int TPB, int K, int NTN, int KSPLIT, int ACT, bool OB16>
__global__ __launch_bounds__(TPB, 2)
void gemm4_kernel(const short* __restrict__ A, const short* __restrict__ Wt,
                  const float* __restrict__ bias, const int* __restrict__ eidx,
                  char* __restrict__ out,
                  size_t wtExpStride, int biasStride, int outLd, size_t outKsStride) {
  constexpr int WAVES = TPB / 64;
  constexpr int WARPS_N = BN / 64, WARPS_M = WAVES / WARPS_N;
  constexpr int WM = BM / WARPS_M, MI = WM / 16;
  constexpr int NT = K / KSPLIT / 64;      // K-tiles (BK=64) per split
  constexpr int JC = 4096 / BM;            // total M-tiles
  constexpr int MTS = CS / BM;             // M-tiles per sample
  __shared__ __align__(16) short As[2][BM * 64];
  __shared__ __align__(16) short Bs[2][BN * 64];
  const int t = threadIdx.x, w = t >> 6, l = t & 63, lr = l & 15, lg = l >> 4;

  // ---- expert-sorted work decode (uniform, register-only) ----
  int exv[CB];
#pragma unroll
  for (int s = 0; s < CB; ++s) exv[s] = eidx[s];
  uint32_t epack = 0;
#pragma unroll
  for (int s = 0; s < CB; ++s) epack |= (uint32_t)exv[s] << (2 * s);
  int c0 = 0, c1 = 0, c2 = 0;
#pragma unroll
  for (int s = 0; s < CB; ++s) {
    c0 += (exv[s] == 0); c1 += (exv[s] == 1); c2 += (exv[s] == 2);
  }
  int p0 = 0, p1 = c0, p2 = c0 + c1, p3 = c0 + c1 + c2;
  uint32_t sortedPack = 0;
#pragma unroll
  for (int s = 0; s < CB; ++s) {
    int e = exv[s];
    int p = (e == 0) ? p0 : (e == 1) ? p1 : (e == 2) ? p2 : p3;
    sortedPack |= (uint32_t)s << (4 * p);
    p0 += (e == 0); p1 += (e == 1); p2 += (e == 2); p3 += (e == 3);
  }
  const int chunk = (int)gridDim.x >> 3;
  const int W_ = ((int)blockIdx.x & 7) * chunk + ((int)blockIdx.x >> 3);
  const int ks = W_ / (JC * NTN);
  const int r1 = W_ - ks * (JC * NTN);
  const int j  = r1 / NTN, nt = r1 - j * NTN;
  const int sample = (int)((sortedPack >> (4 * (j / MTS))) & 7);
  const int jj = j % MTS;
  const int e  = (int)((epack >> (2 * sample)) & 3);
  const int mrow0 = sample * CS + jj * BM;
  const int kBase = ks * NT * 64;

  // ---- staging: linear LDS dest; source col-slot pre-swizzled (slot^row&7) ----
  const int srow = t >> 3;                                  // row within 64-col tile
  const int gcol = (((t & 7) ^ ((t >> 3) & 7)) * 8);        // element offset
  const short* aSrc = A + (size_t)(mrow0 + srow) * K + kBase + gcol;
  const short* bSrc = Wt + (size_t)e * wtExpStride + (size_t)(nt * BN + srow) * K + kBase + gcol;
  constexpr int RPI = TPB / 8;                              // rows per issue
  const size_t issStride = (size_t)RPI * K;

  // ---- frag read offsets: slot (kk*4+lg) ^ (row&7), row&7 == lr&7 ----
  const int wrow = (w / WARPS_N) * WM, wn = (w % WARPS_N) * 64;
  int aoff[2][MI], boff[2][4];
#pragma unroll
  for (int kk = 0; kk < 2; ++kk) {
    const int slot = (kk * 4 + lg) ^ (lr & 7);
#pragma unroll
    for (int mi = 0; mi < MI; ++mi)
      aoff[kk][mi] = (wrow + mi * 16 + lr) * 64 + slot * 8;
#pragma unroll
    for (int ni = 0; ni < 4; ++ni)
      boff[kk][ni] = (wn + ni * 16 + lr) * 64 + slot * 8;
  }

  f32x4 acc[MI][4] = {};

  auto STAGE = [&](int buf, int kt) {
    const short* as = aSrc + (size_t)kt * 64;
#pragma unroll
    for (int i = 0; i < BM / RPI; ++i)
      gload_lds16(as + i * issStride, &As[buf][i * TPB * 8 + t * 8]);
    const short* bs = bSrc + (size_t)kt * 64;
#pragma unroll
    for (int i = 0; i < BN / RPI; ++i)
      gload_lds16(bs + i * issStride, &Bs[buf][i * TPB * 8 + t * 8]);
  };

  STAGE(0, 0);
  for (int kt = 0; kt < NT; ++kt) {
    const int buf = kt & 1;
    if (kt + 1 < NT) { STAGE(buf ^ 1, kt + 1); VMCNT(8); }
    else             { VMCNT(0); }
    __builtin_amdgcn_s_barrier();
    SCHEDB();
    bf16x8 af[2][MI], bfr[2][4];
#pragma unroll
    for (int kk = 0; kk < 2; ++kk) {
#pragma unroll
      for (int ni = 0; ni < 4; ++ni) bfr[kk][ni] = *(const bf16x8*)(&Bs[buf][boff[kk][ni]]);
#pragma unroll
      for (int mi = 0; mi < MI; ++mi) af[kk][mi] = *(const bf16x8*)(&As[buf][aoff[kk][mi]]);
    }
    __builtin_amdgcn_s_setprio(1);
#pragma unroll
    for (int kk = 0; kk < 2; ++kk)
#pragma unroll
      for (int mi = 0; mi < MI; ++mi)
#pragma unroll
        for (int ni = 0; ni < 4; ++ni)
          acc[mi][ni] = __builtin_amdgcn_mfma_f32_16x16x32_bf16(af[kk][mi], bfr[kk][ni],
                                                                acc[mi][ni], 0, 0, 0);
    __builtin_amdgcn_s_setprio(0);
    __builtin_amdgcn_s_barrier();
    SCHEDB();
  }

  // epilogue
  float* outF = (float*)out + (size_t)ks * outKsStride;
#pragma unroll
  for (int ni = 0; ni < 4; ++ni) {
    const int col = nt * BN + wn + ni * 16 + lr;
    const float bv = bias ? bias[e * biasStride + col] : 0.0f;
#pragma unroll
    for (int mi = 0; mi < MI; ++mi) {
      const int row0 = mrow0 + wrow + mi * 16 + lg * 4;
#pragma unroll
      for (int r = 0; r < 4; ++r) {
        float v = acc[mi][ni][r] + bv;
        if (ACT == 1) v = 0.5f * v * (1.0f + erff(v * 0.70710678118654752f));  // exact GELU
        if (OB16) ((short*)out)[(size_t)(row0 + r) * outLd + col] = f2bf(v);
        else      outF[(size_t)(row0 + r) * outLd + col] = v;
      }
    }
  }
}

// ---------------- fused attention ----------------
__global__ void attn_kernel(const short* __restrict__ QKV, const float* __restrict__ mask,
                            short* __restrict__ ctx) {
  __shared__ __align__(16) short Vt[2][64 * 40];
  __shared__ __align__(16) short Pt[4][2][16 * 40];
  const int bh = blockIdx.x;
  const int b = bh / CNH, h = bh % CNH;
  const int qt = blockIdx.y;
  const int t = threadIdx.x, w = t >> 6, l = t & 63, lr = l & 15, lg = l >> 4;

  const size_t bS = (size_t)b * CS;
  const short* Qh = QKV + bS * C3H + h * CDH;
  const short* Kh = Qh + CH;
  const short* Vh = Qh + 2 * CH;
  const float* mrow = mask + bS;

  const int qrow = qt * 64 + w * 16 + lr;
  bf16x8 qa[2];
  qa[0] = *(const bf16x8*)(Qh + (size_t)qrow * C3H + lg * 8);
  qa[1] = *(const bf16x8*)(Qh + (size_t)qrow * C3H + 32 + lg * 8);

  f32x4 o[4] = {};
  float lp[4] = {0.f, 0.f, 0.f, 0.f};

  const int dh = t & 63, kg = t >> 6;
  {
    short v8[8];
#pragma unroll
    for (int j = 0; j < 8; ++j) v8[j] = Vh[(size_t)(kg * 8 + j) * C3H + dh];
    uint32_t p0 = (uint32_t)(uint16_t)v8[0] | ((uint32_t)(uint16_t)v8[1] << 16);
    uint32_t p1 = (uint32_t)(uint16_t)v8[2] | ((uint32_t)(uint16_t)v8[3] << 16);
    uint32_t p2 = (uint32_t)(uint16_t)v8[4] | ((uint32_t)(uint16_t)v8[5] << 16);
    uint32_t p3 = (uint32_t)(uint16_t)v8[6] | ((uint32_t)(uint16_t)v8[7] << 16);
    uint4 pk = {p0, p1, p2, p3};
    *(uint4*)(&Vt[0][dh * 40 + kg * 8]) = pk;
  }

  for (int tt = 0; tt < CS / 32; ++tt) {
    const int k0 = tt * 32;
    __syncthreads();

    f32x4 sacc[2] = {};
#pragma unroll
    for (int n = 0; n < 2; ++n) {
      bf16x8 kb0 = *(const bf16x8*)(Kh + (size_t)(k0 + n * 16 + lr) * C3H + lg * 8);
      bf16x8 kb1 = *(const bf16x8*)(Kh + (size_t)(k0 + n * 16 + lr) * C3H + 32 + lg * 8);
      sacc[n] = __builtin_amdgcn_mfma_f32_16x16x32_bf16(qa[0], kb0, sacc[n], 0, 0, 0);
      sacc[n] = __builtin_amdgcn_mfma_f32_16x16x32_bf16(qa[1], kb1, sacc[n], 0, 0, 0);
    }

    if (tt + 1 < CS / 32) {
      const int k1 = k0 + 32;
      short v8[8];
#pragma unroll
      for (int j = 0; j < 8; ++j) v8[j] = Vh[(size_t)(k1 + kg * 8 + j) * C3H + dh];
      uint32_t p0 = (uint32_t)(uint16_t)v8[0] | ((uint32_t)(uint16_t)v8[1] << 16);
      uint32_t p1 = (uint32_t)(uint16_t)v8[2] | ((uint32_t)(uint16_t)v8[3] << 16);
      uint32_t p2 = (uint32_t)(uint16_t)v8[4] | ((uint32_t)(uint16_t)v8[5] << 16);
      uint32_t p3 = (uint32_t)(uint16_t)v8[6] | ((uint32_t)(uint16_t)v8[7] << 16);
      uint4 pk = {p0, p1, p2, p3};
      *(uint4*)(&Vt[(tt + 1) & 1][dh * 40 + kg * 8]) = pk;
    }

    const int pb = tt & 1;
#pragma unroll
    for (int n = 0; n < 2; ++n) {
      float mv = mrow[k0 + n * 16 + lr];
#pragma unroll
      for (int r = 0; r < 4; ++r) {
        float s = sacc[n][r] * 0.125f + mv;
        float e = __expf(s);
        lp[r] += e;
        Pt[w][pb][(lg * 4 + r) * 40 + n * 16 + lr] = f2bf(e);
      }
    }

    bf16x8 pa = *(const bf16x8*)(&Pt[w][pb][lr * 40 + lg * 8]);
#pragma unroll
    for (int d = 0; d < 4; ++d) {
      bf16x8 vbf = *(const bf16x8*)(&Vt[tt & 1][(d * 16 + lr) * 40 + lg * 8]);
      o[d] = __builtin_amdgcn_mfma_f32_16x16x32_bf16(pa, vbf, o[d], 0, 0, 0);
    }
  }

#pragma unroll
  for (int r = 0; r < 4; ++r) {
    float s = lp[r];
    s += __shfl_xor(s, 1); s += __shfl_xor(s, 2);
    s += __shfl_xor(s, 4); s += __shfl_xor(s, 8);
    lp[r] = 1.0f / s;
  }
#pragma unroll
  for (int d = 0; d < 4; ++d)
#pragma unroll
    for (int r = 0; r < 4; ++r) {
      int row = qt * 64 + w * 16 + lg * 4 + r;
      ctx[(bS + row) * CH + h * CDH + d * 16 + lr] = f2bf(o[d][r] * lp[r]);
    }
}

// ---------------- residual + LayerNorm (1 wave per row) ----------------
__global__ void ln_kernel(const float* __restrict__ xin, const float* __restrict__ res,
                          const float* __restrict__ g, const float* __restrict__ bta,
                          float* __restrict__ out32, short* __restrict__ out16) {
  const int row = blockIdx.x;
  const int l = threadIdx.x;
  const float* xr = xin + (size_t)row * CH;
  const float* rr = res + (size_t)row * CH;
  float4 v[3];
  float sum = 0.f, ss = 0.f;
#pragma unroll
  for (int j = 0; j < 3; ++j) {
    float4 a = *(const float4*)(xr + j * 256 + l * 4);
    float4 b = *(const float4*)(rr + j * 256 + l * 4);
    a.x += b.x; a.y += b.y; a.z += b.z; a.w += b.w;
    v[j] = a;
    sum += a.x + a.y + a.z + a.w;
    ss  += a.x * a.x + a.y * a.y + a.z * a.z + a.w * a.w;
  }
#pragma unroll
  for (int m = 1; m < 64; m <<= 1) { sum += __shfl_xor(sum, m); ss += __shfl_xor(ss, m); }
  const float mean = sum * (1.0f / CH);
  const float var  = ss * (1.0f / CH) - mean * mean;
  const float rstd = rsqrtf(var + 1e-12f);
#pragma unroll
  for (int j = 0; j < 3; ++j) {
    float4 gg = *(const float4*)(g   + j * 256 + l * 4);
    float4 bb = *(const float4*)(bta + j * 256 + l * 4);
    float4 a = v[j], y;
    y.x = (a.x - mean) * rstd * gg.x + bb.x;
    y.y = (a.y - mean) * rstd * gg.y + bb.y;
    y.z = (a.z - mean) * rstd * gg.z + bb.z;
    y.w = (a.w - mean) * rstd * gg.w + bb.w;
    *(float4*)(out32 + (size_t)row * CH + j * 256 + l * 4) = y;
    if (out16) {
      short4 o;
      o.x = f2bf(y.x); o.y = f2bf(y.y); o.z = f2bf(y.z); o.w = f2bf(y.w);
      *(short4*)(out16 + (size_t)row * CH + j * 256 + l * 4) = o;
    }
  }
}

// LN2: sums 2 split-K partials + expert bias + residual, then LayerNorm -> d_out
__global__ void ln2_kernel(const float* __restrict__ p0, const float* __restrict__ p1,
                           const float* __restrict__ res,
                           const float* __restrict__ bout, const int* __restrict__ eidx,
                           const float* __restrict__ g, const float* __restrict__ bta,
                           float* __restrict__ out) {
  const int row = blockIdx.x;
  const int l = threadIdx.x;
  const int e = eidx[row >> 9];
  const float* xr0 = p0 + (size_t)row * CH;
  const float* xr1 = p1 + (size_t)row * CH;
  const float* rr  = res + (size_t)row * CH;
  const float* bo  = bout + (size_t)e * CH;
  float4 v[3];
  float sum = 0.f, ss = 0.f;
#pragma unroll
  for (int j = 0; j < 3; ++j) {
    float4 a = *(const float4*)(xr0 + j * 256 + l * 4);
    float4 c = *(const float4*)(xr1 + j * 256 + l * 4);
    float4 b = *(const float4*)(rr + j * 256 + l * 4);
    float4 bb = *(const float4*)(bo + j * 256 + l * 4);
    a.x += c.x + b.x + bb.x; a.y += c.y + b.y + bb.y;
    a.z += c.z + b.z + bb.z; a.w += c.w + b.w + bb.w;
    v[j] = a;
    sum += a.x + a.y + a.z + a.w;
    ss  += a.x * a.x + a.y * a.y + a.z * a.z + a.w * a.w;
  }
#pragma unroll
  for (int m = 1; m < 64; m <<= 1) { sum += __shfl_xor(sum, m); ss += __shfl_xor(ss, m); }
  const float mean = sum * (1.0f / CH);
  const float var  = ss * (1.0f / CH) - mean * mean;
  const float rstd = rsqrtf(var + 1e-12f);
#pragma unroll
  for (int j = 0; j < 3; ++j) {
    float4 gg = *(const float4*)(g   + j * 256 + l * 4);
    float4 bb = *(const float4*)(bta + j * 256 + l * 4);
    float4 a = v[j], y;
    y.x = (a.x - mean) * rstd * gg.x + bb.x;
    y.y = (a.y - mean) * rstd * gg.y + bb.y;
    y.z = (a.z - mean) * rstd * gg.z + bb.z;
    y.w = (a.w - mean) * rstd * gg.w + bb.w;
    *(float4*)(out + (size_t)row * CH + j * 256 + l * 4) = y;
  }
}

// ---------------- launcher ----------------
extern "C" void kernel_launch(void* const* d_in, const int* in_sizes, int n_in,
                              void* d_out, int out_size, void* d_ws, size_t ws_size,
                              hipStream_t stream) {
  (void)in_sizes; (void)n_in; (void)out_size; (void)ws_size;
  const float* hidden = (const float*)d_in[0];
  const int*   eidx   = (const int*)d_in[1];
  const float* mask   = (const float*)d_in[2];
  const float* Wq   = (const float*)d_in[3];
  const float* bq   = (const float*)d_in[4];
  const float* Wk   = (const float*)d_in[5];
  const float* bk   = (const float*)d_in[6];
  const float* Wv   = (const float*)d_in[7];
  const float* bv   = (const float*)d_in[8];
  const float* Wo   = (const float*)d_in[9];
  const float* bo   = (const float*)d_in[10];
  const float* ln1g = (const float*)d_in[11];
  const float* ln1b = (const float*)d_in[12];
  const float* Wi   = (const float*)d_in[13];
  const float* bi   = (const float*)d_in[14];
  const float* Wout = (const float*)d_in[15];
  const float* bout = (const float*)d_in[16];
  const float* ln2g = (const float*)d_in[17];
  const float* ln2b = (const float*)d_in[18];

  char* ws = (char*)d_ws;
  size_t off = 0;
  auto alloc = [&](size_t bytes) {
    void* p = ws + off;
    off += (bytes + 255) & ~(size_t)255;
    return p;
  };
  const size_t M = (size_t)CB * CS;                    // 4096 rows
  short* Xb    = (short*)alloc(M * CH * 2);            // later reused as x1b
  char*  Rbig  = (char*)alloc(M * CFF * 2);            // QKVb then hmid
  char*  Rcx   = (char*)alloc(M * CH * 4);             // ctxb then x1
  float* ffnp  = (float*)alloc(2 * M * CH * 4);        // split-K partials
  float* qkvbias = (float*)alloc(CE * C3H * 4);
  short* Wqkvt = (short*)alloc((size_t)CE * C3H * CH * 2);   // reused as attn_out
  short* Wot   = (short*)alloc((size_t)CE * CH * CH * 2);
  short* Wit   = (short*)alloc((size_t)CE * CH * CFF * 2);
  short* Wo2t  = (short*)alloc((size_t)CE * CFF * CH * 2);
  short* QKVb     = (short*)Rbig;
  short* hmid     = (short*)Rbig;
  short* ctxb     = (short*)Rcx;
  float* x1       = (float*)Rcx;
  short* x1b      = Xb;
  float* attn_out = (float*)Wqkvt;

  // 1. prep
  const int n4 = (int)(M * CH / 4);
  cvt_bf16_kernel<<<(n4 + 255) / 256, 256, 0, stream>>>(hidden, Xb, n4);
  tpose4_kernel<<<dim3(CH / 64, CH / 64, 4 * CE), 256, 0, stream>>>(Wq, Wk, Wv, Wo, eidx, Wqkvt, Wot);
  tpose_cvt_kernel<<<dim3(CFF / 64, CH / 64, CE), 256, 0, stream>>>(Wi, Wit, eidx, CH, CFF);
  tpose_cvt_kernel<<<dim3(CH / 64, CFF / 64, CE), 256, 0, stream>>>(Wout, Wo2t, eidx, CFF, CH);
  qkv_bias_kernel<<<(CE * C3H + 255) / 256, 256, 0, stream>>>(bq, bk, bv, qkvbias);

  // 2. QKV fused GEMM: 256x256, BK=64, NTN=9 -> grid 144
  gemm4_kernel<256, 256, 512, CH, 9, 1, 0, true><<<144, 512, 0, stream>>>(
      Xb, Wqkvt, qkvbias, eidx, (char*)QKVb, (size_t)C3H * CH, C3H, C3H, 0);
  // 3. attention
  attn_kernel<<<dim3(CB * CNH, CS / 64), 256, 0, stream>>>(QKVb, mask, ctxb);
  // 4. O projection: 128x128, BK=64, NTN=6 -> grid 192 (2 blocks/CU)
  gemm4_kernel<128, 128, 256, CH, 6, 1, 0, false><<<192, 256, 0, stream>>>(
      ctxb, Wot, bo, eidx, (char*)attn_out, (size_t)CH * CH, CH, CH, 0);
  // 5. LN1
  ln_kernel<<<(int)M, 64, 0, stream>>>(attn_out, hidden, ln1g, ln1b, x1, x1b);
  // 6. FFN intermediate + GELU: 256x256, BK=64, NTN=12 -> grid 192
  gemm4_kernel<256, 256, 512, CH, 12, 1, 1, true><<<192, 512, 0, stream>>>(
      x1b, Wit, bi, eidx, (char*)hmid, (size_t)CH * CFF, CFF, CFF, 0);
  // 7. FFN output: 128x128, BK=64, split-K=2, NTN=6 -> grid 384
  gemm4_kernel<128, 128, 256, CFF, 6, 2, 0, false><<<384, 256, 0, stream>>>(
      hmid, Wo2t, nullptr, eidx, (char*)ffnp, (size_t)CFF * CH, CH, CH, M * CH);
  // 8. LN2
  ln2_kernel<<<(int)M, 64, 0, stream>>>(ffnp, ffnp + M * CH, x1, bout, eidx,
                                        ln2g, ln2b, (float*)d_out);
}